// Round 1
// baseline (1090.438 us; speedup 1.0000x reference)
//
#include <hip/hip_runtime.h>
#include <math.h>

#define HW   3136
#define NC   200
#define NB   32
#define SS   56
#define OS   224
#define KS   33
#define GPAD 16

// ---------------------------------------------------------------------------
// K1: per-pixel Mahalanobis distance.
// grid = 3136 blocks (one per pixel, XCD-swizzled), 256 threads (4 waves).
// lane = (b, r): b = lane&31 selects batch, r = lane>>5 selects which of the
// wave's 2 rows of M. Each lane holds delta[b][0..199] in 200 VGPRs; M rows
// stream through an 8-row LDS tile (coalesced float4 loads, broadcast reads).
// ---------------------------------------------------------------------------
__global__ __launch_bounds__(256, 2)
void k_mahal(const float* __restrict__ emb,
             const float* __restrict__ mean,
             const float* __restrict__ icov,
             float* __restrict__ score) {
    const int bid = blockIdx.x;
    const int n = (bid & 7) * 392 + (bid >> 3);   // XCD-contiguous pixel index

    __shared__ __align__(16) float d[NB][204];    // 204: keeps float4 alignment
    __shared__ __align__(16) float mt[8 * NC];    // 8 rows of M
    __shared__ float qs[8][NB];

    // Phase A: delta -> LDS  (6400 elements, 25 iters)
    for (int idx = threadIdx.x; idx < NB * NC; idx += 256) {
        int b = idx / NC, c = idx % NC;
        d[b][c] = emb[(size_t)(b * NC + c) * HW + n] - mean[(size_t)c * HW + n];
    }
    __syncthreads();

    const int lane = threadIdx.x & 63;
    const int w    = threadIdx.x >> 6;
    const int b    = lane & 31;
    const int r    = lane >> 5;

    // Copy this lane's delta row into registers (50 x float4 = 200 VGPRs)
    float4 dreg[50];
#pragma unroll
    for (int j4 = 0; j4 < 50; j4++)
        dreg[j4] = *(const float4*)&d[b][j4 * 4];

    const float* Mn = icov + (size_t)n * (NC * NC);
    float q = 0.0f;

    for (int k = 0; k < 25; k++) {
        // cooperative load of rows [k*8, k*8+8) : 1600 floats = 400 float4
        {
            const float4* src = (const float4*)(Mn + (size_t)k * 8 * NC);
            float4* dst = (float4*)mt;
            for (int idx = threadIdx.x; idx < 400; idx += 256)
                dst[idx] = src[idx];
        }
        __syncthreads();

        const int i = k * 8 + 2 * w + r;
        const float* mrow = mt + (2 * w + r) * NC;

        float4 acc = make_float4(0.f, 0.f, 0.f, 0.f);
#pragma unroll
        for (int j4 = 0; j4 < 50; j4++) {
            float4 m = *(const float4*)&mrow[j4 * 4];
            acc.x += m.x * dreg[j4].x;
            acc.y += m.y * dreg[j4].y;
            acc.z += m.z * dreg[j4].z;
            acc.w += m.w * dreg[j4].w;
        }
        float s = (acc.x + acc.y) + (acc.z + acc.w);
        q += d[b][i] * s;
        __syncthreads();
    }

    qs[2 * w + r][b] = q;
    __syncthreads();

    if (threadIdx.x < NB) {
        int bb = threadIdx.x;
        float t = 0.f;
#pragma unroll
        for (int s = 0; s < 8; s++) t += qs[s][bb];
        t = t > 0.f ? t : 0.f;
        score[(size_t)bb * HW + n] = sqrtf(t);
    }
}

// ---------------------------------------------------------------------------
// K2: bilinear 56 -> 224 (half-pixel centers; jax.resize edge normalization
// is equivalent to index clamping).
// ---------------------------------------------------------------------------
__global__ void k_upsample(const float* __restrict__ score,
                           float* __restrict__ up) {
    int idx = blockIdx.x * 256 + threadIdx.x;
    if (idx >= NB * OS * OS) return;
    int x = idx % OS;
    int y = (idx / OS) % OS;
    int b = idx / (OS * OS);

    float sy = 0.25f * y - 0.375f;
    float sx = 0.25f * x - 0.375f;
    int y0 = (int)floorf(sy); float fy = sy - (float)y0;
    int x0 = (int)floorf(sx); float fx = sx - (float)x0;
    int y0c = min(max(y0, 0), SS - 1), y1c = min(max(y0 + 1, 0), SS - 1);
    int x0c = min(max(x0, 0), SS - 1), x1c = min(max(x0 + 1, 0), SS - 1);

    const float* sb = score + (size_t)b * HW;
    float v00 = sb[y0c * SS + x0c];
    float v01 = sb[y0c * SS + x1c];
    float v10 = sb[y1c * SS + x0c];
    float v11 = sb[y1c * SS + x1c];
    up[idx] = (1.f - fy) * ((1.f - fx) * v00 + fx * v01) +
              fy * ((1.f - fx) * v10 + fx * v11);
}

// ---------------------------------------------------------------------------
// K3: Gaussian weights (matches reference numerics: exp(-x^2/32), normalized)
// ---------------------------------------------------------------------------
__global__ void k_gauss_init(float* __restrict__ g) {
    if (threadIdx.x == 0) {
        float e[KS];
        float sum = 0.f;
        for (int i = 0; i < KS; i++) {
            float x = (float)i - 16.0f;
            e[i] = expf(-(x * x) / 32.0f);
            sum += e[i];
        }
        for (int i = 0; i < KS; i++) g[i] = e[i] / sum;
    }
}

__device__ __forceinline__ int reflect224(int i) {
    if (i < 0) return -i;
    if (i > OS - 1) return 2 * (OS - 1) - i;
    return i;
}

// horizontal 33-tap, reflect padding
__global__ void k_hblur(const float* __restrict__ up,
                        const float* __restrict__ g,
                        float* __restrict__ tmp) {
    int idx = blockIdx.x * 256 + threadIdx.x;
    if (idx >= NB * OS * OS) return;
    int x = idx % OS;
    int row = idx / OS;                  // b*224 + y
    const float* src = up + (size_t)row * OS;
    float acc = 0.f;
#pragma unroll
    for (int t = -GPAD; t <= GPAD; t++) {
        acc += g[t + GPAD] * src[reflect224(x + t)];
    }
    tmp[idx] = acc;
}

// vertical 33-tap, reflect padding
__global__ void k_vblur(const float* __restrict__ tmp,
                        const float* __restrict__ g,
                        float* __restrict__ out) {
    int idx = blockIdx.x * 256 + threadIdx.x;
    if (idx >= NB * OS * OS) return;
    int x = idx % OS;
    int y = (idx / OS) % OS;
    int b = idx / (OS * OS);
    const float* src = tmp + (size_t)b * OS * OS;
    float acc = 0.f;
#pragma unroll
    for (int t = -GPAD; t <= GPAD; t++) {
        acc += g[t + GPAD] * src[(size_t)reflect224(y + t) * OS + x];
    }
    out[idx] = acc;
}

// ---------------------------------------------------------------------------
extern "C" void kernel_launch(void* const* d_in, const int* in_sizes, int n_in,
                              void* d_out, int out_size, void* d_ws, size_t ws_size,
                              hipStream_t stream) {
    const float* emb  = (const float*)d_in[0];   // [32,200,56,56]
    const float* mean = (const float*)d_in[1];   // [200,3136]
    const float* icov = (const float*)d_in[2];   // [3136,200,200]
    // d_in[3] (covariance) unused on mahalanobis path
    float* out = (float*)d_out;                  // [32,1,224,224]

    char* ws = (char*)d_ws;
    float* g     = (float*)ws;                           // 33 floats (256 B slot)
    float* score = (float*)(ws + 256);                   // 32*3136 floats
    float* tmp   = (float*)(ws + 256 + 401408);          // 32*224*224 floats

    const int npix_blocks = HW;                          // 3136
    const int up_blocks   = (NB * OS * OS) / 256;        // 6272 exact

    k_gauss_init<<<1, 64, 0, stream>>>(g);
    k_mahal<<<npix_blocks, 256, 0, stream>>>(emb, mean, icov, score);
    k_upsample<<<up_blocks, 256, 0, stream>>>(score, out);   // out as 'up' buffer
    k_hblur<<<up_blocks, 256, 0, stream>>>(out, g, tmp);
    k_vblur<<<up_blocks, 256, 0, stream>>>(tmp, g, out);
}

// Round 2
// 851.094 us; speedup vs baseline: 1.2812x; 1.2812x over previous
//
#include <hip/hip_runtime.h>
#include <math.h>

#define HW   3136
#define NC   200
#define NB   32
#define SS   56
#define OS   224
#define KS   33
#define GPAD 16

#define KP   224   // K padded to 7 tiles of 32
#define DP   232   // delta LDS row stride (ushorts) — bank-conflict-free b128 reads
#define NP   208   // B-tile rows (13 n-tiles of 16)
#define KTP  40    // B-tile row stride (ushorts): 80 B, 16B-aligned, conflict-free
#define NKT  7

typedef __attribute__((ext_vector_type(8))) short   short8;
typedef __attribute__((ext_vector_type(4))) float   f32x4;

__device__ __forceinline__ unsigned short f2bf(float x) {
    unsigned int u = __builtin_bit_cast(unsigned int, x);
    u += 0x7FFFu + ((u >> 16) & 1u);          // RNE (inputs finite)
    return (unsigned short)(u >> 16);
}
__device__ __forceinline__ float bf2f(unsigned short h) {
    unsigned int u = ((unsigned int)h) << 16;
    return __builtin_bit_cast(float, u);
}

// ---------------------------------------------------------------------------
// K1: per-pixel Mahalanobis via bf16 MFMA.
// One block per pixel. D[32x208] = delta[32x224] x M[224x208] (zero-padded),
// q[b] = sum_j D[b][j]*delta[b][j]. A-frags live in registers; M k-tiles are
// double-buffered through LDS (transposed, fragment-ready), 1 barrier/tile.
// ---------------------------------------------------------------------------
__global__ __launch_bounds__(256, 3)
void k_mahal(const float* __restrict__ emb,
             const float* __restrict__ mean,
             const float* __restrict__ icov,
             float* __restrict__ score) {
    const int bid = blockIdx.x;
    const int n = (bid & 7) * 392 + (bid >> 3);   // XCD-contiguous pixel index
    const int t = threadIdx.x;

    __shared__ __align__(16) unsigned short dd[NB * DP];       // bf16 delta 32x232
    __shared__ __align__(16) unsigned short bt[2][NP * KTP];   // bf16 M tiles, [n][k]
    __shared__ float qs[NB];

    const float* Mn = icov + (size_t)n * (NC * NC);

    // ---- prefetch k-tile 0 (32 rows x 200 cols = 1600 float4) ----
    float4 pf[7];
    {
        const float4* src = (const float4*)Mn;
#pragma unroll
        for (int i = 0; i < 7; i++) {
            int idx = t + i * 256;
            if (idx < 1600) pf[i] = src[idx];
        }
    }

    // ---- phase A: delta -> dd (bf16), zero pads, zero qs, zero bt n-pad ----
    for (int idx = t; idx < NB * NC; idx += 256) {
        int b = idx / NC, c = idx - b * NC;
        float v = emb[(size_t)(b * NC + c) * HW + n] - mean[(size_t)c * HW + n];
        dd[b * DP + c] = f2bf(v);
    }
    for (int idx = t; idx < NB * 32; idx += 256) {             // k-pad 200..231 = 0
        int b = idx >> 5;
        dd[b * DP + NC + (idx & 31)] = 0;
    }
    for (int idx = t; idx < 2 * 8 * KTP; idx += 256) {         // n-pad rows 200..207
        int buf = idx / (8 * KTP), r = idx - buf * (8 * KTP);
        bt[buf][(NC + r / KTP) * KTP + (r % KTP)] = 0;
    }
    if (t < NB) qs[t] = 0.0f;
    __syncthreads();

    const int lane = t & 63;
    const int w    = t >> 6;
    const int col  = lane & 15;
    const int quad = lane >> 4;

    // ---- A fragments in registers: A[m=col][k=quad*8+j], per (mtile,ktile) ----
    short8 aF[2][NKT];
#pragma unroll
    for (int m = 0; m < 2; m++)
#pragma unroll
        for (int kt = 0; kt < NKT; kt++)
            aF[m][kt] = *(const short8*)&dd[(m * 16 + col) * DP + kt * 32 + quad * 8];

    // wave w owns n-tiles nt = w + 4*i (13 tiles total)
    f32x4 acc[2][4];
#pragma unroll
    for (int m = 0; m < 2; m++)
#pragma unroll
        for (int i = 0; i < 4; i++)
            acc[m][i] = (f32x4){0.f, 0.f, 0.f, 0.f};

    // ---- main loop: double-buffered M k-tiles, one barrier per tile ----
#pragma unroll
    for (int kt = 0; kt < NKT; kt++) {
        const int nf4 = (kt < 6) ? 1600 : 400;   // last tile: 8 real rows
        unsigned short* btc = bt[kt & 1];
        // convert + transpose-store prefetched tile kt
#pragma unroll
        for (int i = 0; i < 7; i++) {
            int idx = t + i * 256;
            if (idx < nf4) {
                int k  = idx / 50;
                int n4 = (idx - k * 50) * 4;
                float4 f = pf[i];
                btc[(n4 + 0) * KTP + k] = f2bf(f.x);
                btc[(n4 + 1) * KTP + k] = f2bf(f.y);
                btc[(n4 + 2) * KTP + k] = f2bf(f.z);
                btc[(n4 + 3) * KTP + k] = f2bf(f.w);
            }
        }
        // prefetch tile kt+1
        if (kt < NKT - 1) {
            const int nnext = (kt < 5) ? 1600 : 400;
            const float4* src = (const float4*)(Mn + (size_t)(kt + 1) * 32 * NC);
#pragma unroll
            for (int i = 0; i < 7; i++) {
                int idx = t + i * 256;
                if (idx < nnext) pf[i] = src[idx];
            }
        }
        __syncthreads();
        // MFMA: B frag = B[k=quad*8+j][n=col] from bt[n][k]; shared by both m-tiles
#pragma unroll
        for (int i = 0; i < 4; i++) {
            int nt = w + 4 * i;
            if (nt < 13) {
                short8 bF = *(const short8*)&btc[(nt * 16 + col) * KTP + quad * 8];
                acc[0][i] = __builtin_amdgcn_mfma_f32_16x16x32_bf16(aF[0][kt], bF, acc[0][i], 0, 0, 0);
                acc[1][i] = __builtin_amdgcn_mfma_f32_16x16x32_bf16(aF[1][kt], bF, acc[1][i], 0, 0, 0);
            }
        }
    }

    // ---- epilogue: q[b] = sum_j D[b][j] * delta[b][j] ----
    // D layout: row = quad*4 + r, col = lane&15 (m89-verified)
#pragma unroll
    for (int i = 0; i < 4; i++) {
        int nt = w + 4 * i;
        if (nt < 13) {
#pragma unroll
            for (int m = 0; m < 2; m++) {
                f32x4 a = acc[m][i];
#pragma unroll
                for (int r = 0; r < 4; r++) {
                    int b = m * 16 + quad * 4 + r;
                    float v = a[r] * bf2f(dd[b * DP + nt * 16 + col]);
                    v += __shfl_xor(v, 1);
                    v += __shfl_xor(v, 2);
                    v += __shfl_xor(v, 4);
                    v += __shfl_xor(v, 8);
                    if (col == 0) atomicAdd(&qs[b], v);
                }
            }
        }
    }
    __syncthreads();
    if (t < NB) {
        float q = qs[t];
        score[(size_t)t * HW + n] = sqrtf(q > 0.f ? q : 0.f);
    }
}

// ---------------------------------------------------------------------------
// K2: bilinear 56 -> 224 (half-pixel centers == clamp at edges)
// ---------------------------------------------------------------------------
__global__ void k_upsample(const float* __restrict__ score,
                           float* __restrict__ up) {
    int idx = blockIdx.x * 256 + threadIdx.x;
    if (idx >= NB * OS * OS) return;
    int x = idx % OS;
    int y = (idx / OS) % OS;
    int b = idx / (OS * OS);

    float sy = 0.25f * y - 0.375f;
    float sx = 0.25f * x - 0.375f;
    int y0 = (int)floorf(sy); float fy = sy - (float)y0;
    int x0 = (int)floorf(sx); float fx = sx - (float)x0;
    int y0c = min(max(y0, 0), SS - 1), y1c = min(max(y0 + 1, 0), SS - 1);
    int x0c = min(max(x0, 0), SS - 1), x1c = min(max(x0 + 1, 0), SS - 1);

    const float* sb = score + (size_t)b * HW;
    float v00 = sb[y0c * SS + x0c];
    float v01 = sb[y0c * SS + x1c];
    float v10 = sb[y1c * SS + x0c];
    float v11 = sb[y1c * SS + x1c];
    up[idx] = (1.f - fy) * ((1.f - fx) * v00 + fx * v01) +
              fy * ((1.f - fx) * v10 + fx * v11);
}

// ---------------------------------------------------------------------------
// K3: Gaussian weights (reference numerics: exp(-x^2/32), normalized)
// ---------------------------------------------------------------------------
__global__ void k_gauss_init(float* __restrict__ g) {
    if (threadIdx.x == 0) {
        float e[KS];
        float sum = 0.f;
        for (int i = 0; i < KS; i++) {
            float x = (float)i - 16.0f;
            e[i] = expf(-(x * x) / 32.0f);
            sum += e[i];
        }
        for (int i = 0; i < KS; i++) g[i] = e[i] / sum;
    }
}

__device__ __forceinline__ int reflect224(int i) {
    if (i < 0) return -i;
    if (i > OS - 1) return 2 * (OS - 1) - i;
    return i;
}

__global__ void k_hblur(const float* __restrict__ up,
                        const float* __restrict__ g,
                        float* __restrict__ tmp) {
    int idx = blockIdx.x * 256 + threadIdx.x;
    if (idx >= NB * OS * OS) return;
    int x = idx % OS;
    int row = idx / OS;
    const float* src = up + (size_t)row * OS;
    float acc = 0.f;
#pragma unroll
    for (int t = -GPAD; t <= GPAD; t++) {
        acc += g[t + GPAD] * src[reflect224(x + t)];
    }
    tmp[idx] = acc;
}

__global__ void k_vblur(const float* __restrict__ tmp,
                        const float* __restrict__ g,
                        float* __restrict__ out) {
    int idx = blockIdx.x * 256 + threadIdx.x;
    if (idx >= NB * OS * OS) return;
    int x = idx % OS;
    int y = (idx / OS) % OS;
    int b = idx / (OS * OS);
    const float* src = tmp + (size_t)b * OS * OS;
    float acc = 0.f;
#pragma unroll
    for (int t = -GPAD; t <= GPAD; t++) {
        acc += g[t + GPAD] * src[(size_t)reflect224(y + t) * OS + x];
    }
    out[idx] = acc;
}

// ---------------------------------------------------------------------------
extern "C" void kernel_launch(void* const* d_in, const int* in_sizes, int n_in,
                              void* d_out, int out_size, void* d_ws, size_t ws_size,
                              hipStream_t stream) {
    const float* emb  = (const float*)d_in[0];   // [32,200,56,56]
    const float* mean = (const float*)d_in[1];   // [200,3136]
    const float* icov = (const float*)d_in[2];   // [3136,200,200]
    float* out = (float*)d_out;                  // [32,1,224,224]

    char* ws = (char*)d_ws;
    float* g     = (float*)ws;                           // 33 floats
    float* score = (float*)(ws + 256);                   // 32*3136 floats
    float* tmp   = (float*)(ws + 256 + 401408);          // 32*224*224 floats

    const int up_blocks = (NB * OS * OS) / 256;          // 6272

    k_gauss_init<<<1, 64, 0, stream>>>(g);
    k_mahal<<<HW, 256, 0, stream>>>(emb, mean, icov, score);
    k_upsample<<<up_blocks, 256, 0, stream>>>(score, out);
    k_hblur<<<up_blocks, 256, 0, stream>>>(out, g, tmp);
    k_vblur<<<up_blocks, 256, 0, stream>>>(tmp, g, out);
}